// Round 8
// baseline (145.345 us; speedup 1.0000x reference)
//
#include <hip/hip_runtime.h>

constexpr int Bn = 8, S = 2048, E = 1024, H = 64;
constexpr float SCALE = 0.03125f;     // E^-0.5 (folded into q)
constexpr float LOG2E = 1.44269504f;

typedef __attribute__((ext_vector_type(8))) short short8;  // 8 bf16
typedef __attribute__((ext_vector_type(4))) float f32x4;   // MFMA C/D

__device__ __forceinline__ unsigned short f2bf(float f) {
  unsigned u = __builtin_bit_cast(unsigned, f);
  u += 0x7fffu + ((u >> 16) & 1u);    // RNE
  return (unsigned short)(u >> 16);
}
__device__ __forceinline__ ushort4 f4bf(float4 f) {
  return make_ushort4(f2bf(f.x), f2bf(f.y), f2bf(f.z), f2bf(f.w));
}

// ---------- W [1024][64] fp32 -> WT3 [3][64][1024] bf16 ----------
__global__ __launch_bounds__(256) void wtrans_kernel(
    const float* __restrict__ Wq, const float* __restrict__ Wk,
    const float* __restrict__ Wv, unsigned short* __restrict__ WT3) {
  __shared__ unsigned short tb[64][72];
  const int m = blockIdx.x >> 4;
  const int e0 = (blockIdx.x & 15) * 64;
  const float* W = (m == 0) ? Wq : (m == 1) ? Wk : Wv;
  const int t = threadIdx.x;
#pragma unroll
  for (int it = 0; it < 4; ++it) {
    int idx = t + it * 256;
    int r = idx >> 4, c4 = idx & 15;
    float4 f = ((const float4*)(W + (long)(e0 + r) * H))[c4];
    *(ushort4*)&tb[r][c4 * 4] = f4bf(f);
  }
  __syncthreads();
#pragma unroll
  for (int it = 0; it < 4; ++it) {
    int idx = t + it * 256;
    int h = idx >> 4, e4 = idx & 15;
    ushort4 u = make_ushort4(tb[e4 * 4 + 0][h], tb[e4 * 4 + 1][h],
                             tb[e4 * 4 + 2][h], tb[e4 * 4 + 3][h]);
    ((ushort4*)(WT3 + (long)(m * 64 + h) * E + e0))[e4] = u;
  }
}

// ---------- QKV GEMM, m97-style: M=32 x N=192, BK=128, LDS-dense ----------
// (unchanged from R7: 60.5 -> ~29 us)
__global__ __launch_bounds__(256) void qkv_kernel(
    const float* __restrict__ x, const unsigned short* __restrict__ WT3,
    unsigned short* __restrict__ q, unsigned short* __restrict__ kk,
    unsigned short* __restrict__ vT) {
  __shared__ unsigned short xs[32][136];    // [seq-row][e in chunk]
  __shared__ unsigned short ws[192][136];   // [out-col j][e in chunk]
  const int t = threadIdx.x;
  const int w = t >> 6, lane = t & 63, l15 = lane & 15, g = lane >> 4;
  const long row0 = (long)blockIdx.x * 32;
  const int xrow = t >> 5, xslot = t & 31;  // x: 8 rows x 32 float4 / iter
  const int wrow = t >> 4, wslot = t & 15;  // W: 16 rows x 16 short8 / iter

  f32x4 acc[2][3];
#pragma unroll
  for (int rt = 0; rt < 2; ++rt)
#pragma unroll
    for (int ct = 0; ct < 3; ++ct) acc[rt][ct] = f32x4{0.f, 0.f, 0.f, 0.f};

  float4 px[4];
  short8 pw[12];
#pragma unroll
  for (int it = 0; it < 4; ++it)
    px[it] = ((const float4*)(x + (row0 + xrow + it * 8) * E))[xslot];
#pragma unroll
  for (int it = 0; it < 12; ++it)
    pw[it] = *(const short8*)(WT3 + (long)(wrow + it * 16) * E + wslot * 8);
#pragma unroll
  for (int it = 0; it < 4; ++it)
    *(ushort4*)&xs[xrow + it * 8][xslot * 4] = f4bf(px[it]);
#pragma unroll
  for (int it = 0; it < 12; ++it)
    *(short8*)&ws[wrow + it * 16][wslot * 8] = pw[it];

  for (int c = 0; c < 8; ++c) {             // 8 chunks of 128 e
    __syncthreads();
    if (c < 7) {
      const int e0 = (c + 1) * 128;
#pragma unroll
      for (int it = 0; it < 4; ++it)
        px[it] = ((const float4*)(x + (row0 + xrow + it * 8) * E + e0))[xslot];
#pragma unroll
      for (int it = 0; it < 12; ++it)
        pw[it] = *(const short8*)(WT3 + (long)(wrow + it * 16) * E + e0 + wslot * 8);
    }
#pragma unroll
    for (int kh = 0; kh < 4; ++kh) {
      short8 a0 = *(const short8*)&xs[l15][kh * 32 + g * 8];
      short8 a1 = *(const short8*)&xs[16 + l15][kh * 32 + g * 8];
#pragma unroll
      for (int ct = 0; ct < 3; ++ct) {
        short8 b = *(const short8*)&ws[w * 48 + ct * 16 + l15][kh * 32 + g * 8];
        acc[0][ct] = __builtin_amdgcn_mfma_f32_16x16x32_bf16(a0, b, acc[0][ct], 0, 0, 0);
        acc[1][ct] = __builtin_amdgcn_mfma_f32_16x16x32_bf16(a1, b, acc[1][ct], 0, 0, 0);
      }
    }
    __syncthreads();
    if (c < 7) {
#pragma unroll
      for (int it = 0; it < 4; ++it)
        *(ushort4*)&xs[xrow + it * 8][xslot * 4] = f4bf(px[it]);
#pragma unroll
      for (int it = 0; it < 12; ++it)
        *(short8*)&ws[wrow + it * 16][wslot * 8] = pw[it];
    }
  }

  const int bb = (int)(row0 >> 11);
  const int srow = (int)(row0 & 2047);
#pragma unroll
  for (int ct = 0; ct < 3; ++ct) {
    const int col = w * 48 + ct * 16 + l15;
    const int mm = col >> 6, ch = col & 63;
#pragma unroll
    for (int rt = 0; rt < 2; ++rt) {
      const int srl = rt * 16 + g * 4;
      if (mm == 0) {
#pragma unroll
        for (int r = 0; r < 4; ++r)
          q[(row0 + srl + r) * H + ch] = f2bf(acc[rt][ct][r] * SCALE);
      } else if (mm == 1) {
#pragma unroll
        for (int r = 0; r < 4; ++r)
          kk[(row0 + srl + r) * H + ch] = f2bf(acc[rt][ct][r]);
      } else {
        ushort4 v4 = make_ushort4(f2bf(acc[rt][ct][0]), f2bf(acc[rt][ct][1]),
                                  f2bf(acc[rt][ct][2]), f2bf(acc[rt][ct][3]));
        *(ushort4*)(vT + ((long)bb * H + ch) * S + srow + srl) = v4;
      }
    }
  }
}

// ---------- causal flash attention v4: S^T softmax + dense LDS staging ----
// Block = 256 thr / 4 waves: wave = (qg = w&1: 16-q-row group, hf = w>>1:
// 32-key half). Q-tile 32, K-tile 64 staged dense in LDS (K rows and vT
// rows are 128B-contiguous -> ~8 line-reqs per staging instr, vs 64 for the
// old direct frag loads). Per-lane online softmax (C col = l15 = q-row).
// grid 512: blocks i, i+256 have qt summing to 63 (33 iters combined) and
// co-reside on one CU. End: LDS merge of the two key-halves per q-group.
__global__ __launch_bounds__(256, 2) void attn_kernel(
    const unsigned short* __restrict__ q, const unsigned short* __restrict__ k,
    const unsigned short* __restrict__ vT, float* __restrict__ out) {
  __shared__ unsigned short ks[64][72];     // [key][h]
  __shared__ unsigned short vt[64][72];     // [h][key]
  __shared__ unsigned short pl[4][16][40];  // per-wave P^T round-trip
  __shared__ float Om[2][64][20];           // hf=1 partial O^T [h][qrow]
  __shared__ float ms[2][16], ls[2][16];
  const int t = threadIdx.x;
  const int w = t >> 6, lane = t & 63, l15 = lane & 15, g = lane >> 4;
  const int qg = w & 1, hf = w >> 1;
  const int b = blockIdx.x & 7;
  const int idx = blockIdx.x >> 3;
  const int qt = (idx < 32) ? idx : 95 - idx;     // pair sums to 63
  const int qrow0 = qt * 32 + qg * 16;
  const int nt = (32 * qt + 95) >> 6;             // K64 tiles (diag = last)
  const unsigned short* kb = k + (long)b * S * H;
  const unsigned short* vb = vT + (long)b * H * S;
  const unsigned short* qp = q + ((long)b * S + qrow0 + l15) * H + g * 8;
  short8 bq0 = *(const short8*)qp;                // Q B-frag: n=l15=qrow, k=h
  short8 bq1 = *(const short8*)(qp + 32);

  f32x4 O[4];
#pragma unroll
  for (int c = 0; c < 4; ++c) O[c] = f32x4{0.f, 0.f, 0.f, 0.f};
  float m_ = -1e30f, l_ = 0.f;

  // dense cooperative staging: 64 rows x 8 short8 slots, 2 slots/thread
  short8 pk[2], pv[2];
#pragma unroll
  for (int it = 0; it < 2; ++it) {
    const int idxs = t + it * 256;
    const int r = idxs >> 3, s8 = idxs & 7;
    pk[it] = *(const short8*)(kb + (long)r * H + s8 * 8);
    pv[it] = *(const short8*)(vb + (long)r * S + s8 * 8);
  }
#pragma unroll
  for (int it = 0; it < 2; ++it) {
    const int idxs = t + it * 256;
    const int r = idxs >> 3, s8 = idxs & 7;
    *(short8*)&ks[r][s8 * 8] = pk[it];
    *(short8*)&vt[r][s8 * 8] = pv[it];
  }

  for (int kt = 0; kt < nt; ++kt) {
    __syncthreads();                              // staged tile visible
    if (kt + 1 < nt) {                            // dense prefetch of kt+1
#pragma unroll
      for (int it = 0; it < 2; ++it) {
        const int idxs = t + it * 256;
        const int r = idxs >> 3, s8 = idxs & 7;
        pk[it] = *(const short8*)(kb + (long)((kt + 1) * 64 + r) * H + s8 * 8);
        pv[it] = *(const short8*)(vb + (long)r * S + (kt + 1) * 64 + s8 * 8);
      }
    }
    // ---- S^T = K Q^T for this wave's key half ----
    f32x4 sc[2];
#pragma unroll
    for (int c = 0; c < 2; ++c) {
      sc[c] = f32x4{0.f, 0.f, 0.f, 0.f};
      short8 a0 = *(const short8*)&ks[hf * 32 + c * 16 + l15][g * 8];
      short8 a1 = *(const short8*)&ks[hf * 32 + c * 16 + l15][32 + g * 8];
      sc[c] = __builtin_amdgcn_mfma_f32_16x16x32_bf16(a0, bq0, sc[c], 0, 0, 0);
      sc[c] = __builtin_amdgcn_mfma_f32_16x16x32_bf16(a1, bq1, sc[c], 0, 0, 0);
    }
    if (kt == nt - 1) {                           // only diag tile masks
#pragma unroll
      for (int c = 0; c < 2; ++c)
#pragma unroll
        for (int r = 0; r < 4; ++r)
          if (kt * 64 + hf * 32 + c * 16 + g * 4 + r > qrow0 + l15)
            sc[c][r] = -1e30f;
    }
    // ---- per-lane online softmax (2 shuffles for max, 2 for sum) ----
    float mx = fmaxf(fmaxf(sc[0][0], sc[0][1]), fmaxf(sc[0][2], sc[0][3]));
    mx = fmaxf(mx, fmaxf(fmaxf(sc[1][0], sc[1][1]), fmaxf(sc[1][2], sc[1][3])));
    mx = fmaxf(mx, __shfl_xor(mx, 16));
    mx = fmaxf(mx, __shfl_xor(mx, 32));
    const float mn = fmaxf(m_, mx);
    const float valid = (mn > -1e29f) ? 1.0f : 0.0f;  // all-masked guard
    const float al = exp2f((m_ - mn) * LOG2E);
    float sum = 0.f;
#pragma unroll
    for (int c = 0; c < 2; ++c)
#pragma unroll
      for (int r = 0; r < 4; ++r) {
        float pe = exp2f((sc[c][r] - mn) * LOG2E) * valid;
        sc[c][r] = pe;
        sum += pe;
      }
    sum += __shfl_xor(sum, 16);
    sum += __shfl_xor(sum, 32);
    l_ = l_ * al + sum;
    m_ = mn;
    // ---- P^T -> per-wave LDS (2 b64 writes), O rescale ----
#pragma unroll
    for (int c = 0; c < 2; ++c) {
      ushort4 p4 = make_ushort4(f2bf(sc[c][0]), f2bf(sc[c][1]),
                                f2bf(sc[c][2]), f2bf(sc[c][3]));
      *(ushort4*)&pl[w][l15][c * 16 + g * 4] = p4;
    }
#pragma unroll
    for (int c = 0; c < 4; ++c)
#pragma unroll
      for (int r = 0; r < 4; ++r) O[c][r] *= al;
    // ---- O^T += V^T P^T (K=32 over this wave's key half) ----
    short8 bp = *(const short8*)&pl[w][l15][g * 8];
#pragma unroll
    for (int c = 0; c < 4; ++c) {
      short8 av = *(const short8*)&vt[c * 16 + l15][hf * 32 + g * 8];
      O[c] = __builtin_amdgcn_mfma_f32_16x16x32_bf16(av, bp, O[c], 0, 0, 0);
    }
    __syncthreads();                              // LDS reads done
    if (kt + 1 < nt) {
#pragma unroll
      for (int it = 0; it < 2; ++it) {
        const int idxs = t + it * 256;
        const int r = idxs >> 3, s8 = idxs & 7;
        *(short8*)&ks[r][s8 * 8] = pk[it];
        *(short8*)&vt[r][s8 * 8] = pv[it];
      }
    }
  }

  // ---- merge the two key-halves of each q-group ----
  if (hf == 1) {
#pragma unroll
    for (int c = 0; c < 4; ++c)
#pragma unroll
      for (int r = 0; r < 4; ++r)
        Om[qg][c * 16 + g * 4 + r][l15] = O[c][r];
    if (g == 0) { ms[qg][l15] = m_; ls[qg][l15] = l_; }
  }
  __syncthreads();
  if (hf == 0) {
    const float m1 = ms[qg][l15], l1 = ls[qg][l15];
    const float mstar = fmaxf(m_, m1);
    const float f0 = exp2f((m_ - mstar) * LOG2E);
    const float f1 = exp2f((m1 - mstar) * LOG2E);
    const float inv = 1.0f / (l_ * f0 + l1 * f1);
    float* op = out + ((long)b * S + qrow0 + l15) * H;
#pragma unroll
    for (int c = 0; c < 4; ++c) {
      float4 o;
      o.x = (O[c][0] * f0 + Om[qg][c * 16 + g * 4 + 0][l15] * f1) * inv;
      o.y = (O[c][1] * f0 + Om[qg][c * 16 + g * 4 + 1][l15] * f1) * inv;
      o.z = (O[c][2] * f0 + Om[qg][c * 16 + g * 4 + 2][l15] * f1) * inv;
      o.w = (O[c][3] * f0 + Om[qg][c * 16 + g * 4 + 3][l15] * f1) * inv;
      *(float4*)(op + c * 16 + g * 4) = o;
    }
  }
}

extern "C" void kernel_launch(void* const* d_in, const int* in_sizes, int n_in,
                              void* d_out, int out_size, void* d_ws, size_t ws_size,
                              hipStream_t stream) {
  const float* x  = (const float*)d_in[0];
  const float* Wq = (const float*)d_in[1];
  const float* Wk = (const float*)d_in[2];
  const float* Wv = (const float*)d_in[3];
  float* outp = (float*)d_out;
  unsigned short* WT3 = (unsigned short*)d_ws;                       // 384 KB
  unsigned short* q  = (unsigned short*)((char*)d_ws + 512 * 1024);  // 2 MB each
  unsigned short* kk = q + (size_t)Bn * S * H;
  unsigned short* vT = kk + (size_t)Bn * S * H;
  wtrans_kernel<<<dim3(48), dim3(256), 0, stream>>>(Wq, Wk, Wv, WT3);
  qkv_kernel<<<dim3((Bn * S) / 32), dim3(256), 0, stream>>>(x, WT3, q, kk, vT);
  attn_kernel<<<dim3(Bn * 64), dim3(256), 0, stream>>>(q, kk, vT, outp);
}